// Round 5
// baseline (177.419 us; speedup 1.0000x reference)
//
#include <hip/hip_runtime.h>

#define DEVI __device__ __forceinline__

typedef short bf16x8 __attribute__((ext_vector_type(8)));
typedef float f32x4 __attribute__((ext_vector_type(4)));
typedef unsigned short u16;
typedef unsigned int u32;

// Problem constants
static constexpr int Bn = 2, S = 2048, E = 1024, H = 16, D = 64;
static constexpr int Mrows = Bn * S;          // 4096
static constexpr int N_QKV = 3 * E;           // 3072

DEVI u16 f2b(float f) {
  union { float f; u32 u; } c; c.f = f;
  return (u16)((c.u + 0x7FFFu + ((c.u >> 16) & 1u)) >> 16);
}

DEVI bf16x8 ld8(const u16* p) {
  union { uint4 u; bf16x8 v; } c;
  c.u = *reinterpret_cast<const uint4*>(p);
  return c.v;
}

#define MFMA(a, b, c) __builtin_amdgcn_mfma_f32_16x16x32_bf16(a, b, c, 0, 0, 0)

// global -> LDS async copy, 16B per lane. LDS dest must be wave-uniform-base + lane*16.
#define G2L16(gptr, lptr) \
  __builtin_amdgcn_global_load_lds((const __attribute__((address_space(1))) void*)(gptr), \
                                   (__attribute__((address_space(3))) void*)(lptr), 16, 0, 0)

// ---------------- Fused prep: transposes FIRST, conv LAST (r14 order) ----------------
__global__ __launch_bounds__(256) void prep(const float* __restrict__ x,
                                            const float* __restrict__ w_attn,
                                            const float* __restrict__ w_proj,
                                            u16* __restrict__ xb, u16* __restrict__ wabT,
                                            u16* __restrict__ wpbT) {
  __shared__ float t[32][33];
  int blk = blockIdx.x, tid = threadIdx.x;
  if (blk >= 4096) {
    int i = (blk - 4096) * 256 + tid;          // n4 = 4096*1024/4 = 1048576
    float4 f = reinterpret_cast<const float4*>(x)[i];
    ushort4 u;
    u.x = f2b(f.x); u.y = f2b(f.y); u.z = f2b(f.z); u.w = f2b(f.w);
    reinterpret_cast<ushort4*>(xb)[i] = u;
    return;
  }
  const float* in; u16* out; int R, C, bx, by;
  if (blk < 3072) {
    in = w_attn; out = wabT; R = E; C = N_QKV;  // 96 x 32 tiles
    bx = (blk % 96) * 32; by = (blk / 96) * 32;
  } else {
    int q = blk - 3072;                         // 32 x 32 tiles
    in = w_proj; out = wpbT; R = E; C = E;
    bx = (q % 32) * 32; by = (q / 32) * 32;
  }
  int tx = tid & 31, ty = tid >> 5;             // 32 x 8
#pragma unroll
  for (int k = 0; k < 32; k += 8)
    t[ty + k][tx] = in[(size_t)(by + ty + k) * C + bx + tx];
  __syncthreads();
#pragma unroll
  for (int k = 0; k < 32; k += 8)
    out[(size_t)(bx + ty + k) * R + by + tx] = f2b(t[tx][ty + k]);
}

// ---------------- GEMM1: qkv = xb @ wabT^T, 128x64 tile, BK=64, XOR swizzle (r14) ---------
// r19: 128x128 tile REVERTED (r18: 510 TF, 50.6us, Occ 14%). Short K (16 steps) +
// scatter epilogue + halved grid lose more to occupancy/tails than doubled B-reuse gains.
// Q pre-scaled by log2e/8 so attn scores arrive in log2 domain (exp2 = bare v_exp_f32).
__global__ __launch_bounds__(256) void gemm_qkv(const u16* __restrict__ A, const u16* __restrict__ BT,
                                                u16* __restrict__ Qb, u16* __restrict__ Kb,
                                                u16* __restrict__ VbT) {
  constexpr int K = 1024, BK = 64;
  __shared__ __align__(16) u16 As[128 * BK];   // 16 KB, swizzled rows of 8 16B-groups
  __shared__ __align__(16) u16 Bs[64 * BK];    // 8 KB
  int tid = threadIdx.x;
  int w = tid >> 6, lane = tid & 63, quad = lane >> 4, l15 = lane & 15;
  int m0 = blockIdx.x * 128, n0 = blockIdx.y * 64;
  int mw = (w >> 1) * 64, nw = (w & 1) * 32;   // wave-tile 64x32
  const u16* Ab = A + (size_t)m0 * K;
  const u16* Bb = BT + (size_t)n0 * K;
  f32x4 acc[4][2] = {};
  for (int k0 = 0; k0 < K; k0 += BK) {
#pragma unroll
    for (int j = 0; j < 4; j++) {
      int L = j * 256 + tid;
      int row = L >> 3, cg = (L & 7) ^ (row & 7);
      G2L16(Ab + (size_t)row * K + k0 + cg * 8, (char*)As + L * 16);
    }
#pragma unroll
    for (int j = 0; j < 2; j++) {
      int L = j * 256 + tid;
      int row = L >> 3, cg = (L & 7) ^ (row & 7);
      G2L16(Bb + (size_t)row * K + k0 + cg * 8, (char*)Bs + L * 16);
    }
    __syncthreads();
#pragma unroll
    for (int kk = 0; kk < 2; kk++) {
      int sg = ((kk << 2) | quad) ^ (l15 & 7);   // swizzled 16B-group for this lane
      bf16x8 a[4], b[2];
#pragma unroll
      for (int i = 0; i < 4; i++) a[i] = ld8(&As[(mw + i * 16 + l15) * BK + sg * 8]);
#pragma unroll
      for (int i = 0; i < 2; i++) b[i] = ld8(&Bs[(nw + i * 16 + l15) * BK + sg * 8]);
#pragma unroll
      for (int mb = 0; mb < 4; mb++)
#pragma unroll
        for (int nb = 0; nb < 2; nb++)
          acc[mb][nb] = MFMA(a[mb], b[nb], acc[mb][nb]);
    }
    __syncthreads();
  }
#pragma unroll
  for (int mb = 0; mb < 4; mb++) {
    int m = m0 + mw + mb * 16 + quad * 4;      // rows m..m+3 (tiles never straddle batch)
    int b = m >> 11, s = m & 2047;
#pragma unroll
    for (int nb = 0; nb < 2; nb++) {
      int n = n0 + nw + nb * 16 + l15;
      int sec = n >> 10, e = n & 1023, h = e >> 6, d = e & 63;
      int bh = b * H + h;
      if (sec == 0) {
#pragma unroll
        for (int r = 0; r < 4; r++)
          Qb[((size_t)bh * S + s + r) * D + d] = f2b(acc[mb][nb][r] * 0.1803368801111244f);
      } else if (sec == 1) {
#pragma unroll
        for (int r = 0; r < 4; r++)
          Kb[((size_t)bh * S + s + r) * D + d] = f2b(acc[mb][nb][r]);
      } else {
        ushort4 v;
        v.x = f2b(acc[mb][nb][0]); v.y = f2b(acc[mb][nb][1]);
        v.z = f2b(acc[mb][nb][2]); v.w = f2b(acc[mb][nb][3]);
        *reinterpret_cast<ushort4*>(VbT + ((size_t)bh * D + d) * S + s) = v;
      }
    }
  }
}

// ---------------- Flash attention: REGISTER-P (r21), dbuf staging, counted vmcnt ----------
// r20 (dbuf + counted vmcnt) was NEUTRAL vs round-0 -> staging was never the critical
// path; the serial chain was the P LDS round-trip (MFMA -> exp2/pack -> ds_write P ->
// lgkmcnt -> ds_read P -> MFMA). r21 removes P from LDS with ZERO cross-lane traffic:
// the MFMA B-operand's k-order within a 32-key chunk is arbitrary as long as V is read
// in the SAME order. QK^T leaves lane (quad,l15) holding keys {s*16+quad*4+r}; under the
// bijection kappa=quad*8+j -> (j<4 ? quad*4+j : 16+quad*4+j-4) the lane's own packed
// u32s (pa0,pb0,pa1,pb1) ARE the B operand. V is read with the same permutation: two
// ds_read_b64 at key offsets ch*32+quad*4 and ch*32+16+quad*4 (instead of one b128).
// LDS 41984 -> 32768 (K/V dbuf only) -> 4 blocks/CU = 16 waves (+33%); per-chunk chain
// is now register-only. All 1024 blocks co-resident -> balanced qt permutation
// (quadruples {ga,15-ga,16+ga,31-ga} sum 62); same-bh -> same-XCD kept (blk%8==bh%8).
// Sync skeleton = r20: issue next chunk's G2L16 BEFORE compute, s_waitcnt vmcnt(4)
// (never 0 mid-loop) + raw s_barrier + sched_barrier(0); lgkmcnt(0)-only drain at the
// tail barrier (NOT __syncthreads -- that would drain vmcnt and kill the prefetch).
__global__ __launch_bounds__(256, 4) void attn(const u16* __restrict__ Qb, const u16* __restrict__ Kb,
                                               const u16* __restrict__ VbT, u16* __restrict__ Yb) {
  __shared__ __align__(16) u16 Ks[2][64 * 64];  // swizzled: (row, cg) at row*64 + (cg^(row&7))*8
  __shared__ __align__(16) u16 Vs[2][64 * 64];  // swizzled: (d, cg) at d*64 + (cg^(d&7))*8
  int w = threadIdx.x >> 6, lane = threadIdx.x & 63, quad = lane >> 4, l15 = lane & 15;
  int bh = blockIdx.x & 31;
  int g = blockIdx.x >> 5;           // 0..31
  int ga = g & 7, gb = g >> 3;
  int qt = ((gb & 2) << 3) + ((gb & 1) ? (15 - ga) : ga);   // balanced work permutation
  int b = bh >> 4, h = bh & 15;
  int nc = qt + 1;                   // 64-key chunks this block needs

  const u16* Kbh = Kb + (size_t)bh * S * D;
  const u16* Vbh = VbT + (size_t)bh * D * S;

  int q_base = qt * 64 + w * 16;
  int qrow = q_base + l15;
  int kmax = q_base + 16;            // causal: this wave needs keys [0, kmax)

  const u16* Qp = Qb + ((size_t)bh * S + qrow) * D + quad * 8;
  bf16x8 bq0 = ld8(Qp), bq1 = ld8(Qp + 32);

  float lpart = 0.f;
  f32x4 o[4] = {};

  // ---- prologue: stage chunk 0 into buffer 0 (4 G2L16 per wave) ----
#pragma unroll
  for (int j = 0; j < 2; j++) {
    int L = (w * 2 + j) * 64 + lane;           // 0..511
    int row = L >> 3, cg = (L & 7) ^ (row & 7);
    G2L16(Kbh + (size_t)row * D + cg * 8, (char*)Ks[0] + L * 16);
  }
#pragma unroll
  for (int j = 0; j < 2; j++) {
    int L = (w * 2 + j) * 64 + lane;
    int row = L >> 3, cg = (L & 7) ^ (row & 7);
    G2L16(Vbh + (size_t)row * S + cg * 8, (char*)Vs[0] + L * 16);
  }

  for (int c = 0; c < nc; c++) {
    int kbase = c * 64;
    int cur = c & 1;
    if (c + 1 < nc) {
      // ---- issue next chunk's staging into the other buffer, then counted wait ----
      const u16* Kg = Kbh + (size_t)(kbase + 64) * D;
      const u16* Vg = Vbh + (kbase + 64);
#pragma unroll
      for (int j = 0; j < 2; j++) {
        int L = (w * 2 + j) * 64 + lane;
        int row = L >> 3, cg = (L & 7) ^ (row & 7);
        G2L16(Kg + (size_t)row * D + cg * 8, (char*)Ks[cur ^ 1] + L * 16);
      }
#pragma unroll
      for (int j = 0; j < 2; j++) {
        int L = (w * 2 + j) * 64 + lane;
        int row = L >> 3, cg = (L & 7) ^ (row & 7);
        G2L16(Vg + (size_t)row * S + cg * 8, (char*)Vs[cur ^ 1] + L * 16);
      }
      asm volatile("s_waitcnt vmcnt(4)" ::: "memory");   // chunk c landed; c+1 in flight
    } else {
      asm volatile("s_waitcnt vmcnt(0)" ::: "memory");   // final chunk: drain
    }
    __builtin_amdgcn_s_barrier();
    __builtin_amdgcn_sched_barrier(0);

    const u16* Kc = Ks[cur];
    const u16* Vc = Vs[cur];

    // ---- per 32-key chunk: QK^T pair -> packed P in registers -> PV ----
#pragma unroll
    for (int ch = 0; ch < 2; ch++) {
      int kc = kbase + ch * 32;
      if (kc < kmax) {               // wave-uniform
        u32 pw0 = 0, pw1 = 0, pw2 = 0, pw3 = 0;   // pa_s0, pb_s0, pa_s1, pb_s1
#pragma unroll
        for (int s = 0; s < 2; s++) {
          int kb = kc + s * 16;
          if (kb < kmax) {           // wave-uniform
            int row = (ch * 2 + s) * 16 + l15;
            bf16x8 ak0 = ld8(&Kc[row * 64 + ((quad ^ (row & 7)) * 8)]);
            bf16x8 ak1 = ld8(&Kc[row * 64 + (((quad + 4) ^ (row & 7)) * 8)]);
            f32x4 z = {};
            __builtin_amdgcn_s_setprio(1);
            z = MFMA(ak0, bq0, z);
            z = MFMA(ak1, bq1, z);
            __builtin_amdgcn_s_setprio(0);
            if (kb == q_base) {      // diagonal subtile: mask k > q
#pragma unroll
              for (int r = 0; r < 4; r++)
                if (quad * 4 + r > l15) z[r] = -1e30f;
            }
            float p0 = __builtin_amdgcn_exp2f(z[0]);
            float p1 = __builtin_amdgcn_exp2f(z[1]);
            float p2 = __builtin_amdgcn_exp2f(z[2]);
            float p3 = __builtin_amdgcn_exp2f(z[3]);
            lpart += (p0 + p1) + (p2 + p3);
            union { float f; u32 u; } c0, c1, c2, c3;
            c0.f = p0; c1.f = p1; c2.f = p2; c3.f = p3;
            u32 pa = __builtin_amdgcn_perm(c1.u + 0x8000u, c0.u + 0x8000u, 0x07060302u);
            u32 pb = __builtin_amdgcn_perm(c3.u + 0x8000u, c2.u + 0x8000u, 0x07060302u);
            if (s == 0) { pw0 = pa; pw1 = pb; } else { pw2 = pa; pw3 = pb; }
          }
        }
        // B operand = own registers under key perm: kappa=quad*8+j -> keys
        // {kc+quad*4+0..3, kc+16+quad*4+0..3}. V read with the SAME key order.
        union { u32 u[4]; bf16x8 v; } bp;
        bp.u[0] = pw0; bp.u[1] = pw1; bp.u[2] = pw2; bp.u[3] = pw3;
        int cg0 = ch * 4 + (quad >> 1), cg1 = cg0 + 2;   // 16B-groups of the two b64s
        int woff = (quad & 1) * 4;                       // u16 offset within group
        __builtin_amdgcn_s_setprio(1);
#pragma unroll
        for (int dd = 0; dd < 4; dd++) {
          int rv = dd * 16 + l15;
          union { uint2 d[2]; bf16x8 v; } av;
          av.d[0] = *reinterpret_cast<const uint2*>(&Vc[rv * 64 + ((cg0 ^ (rv & 7)) * 8) + woff]);
          av.d[1] = *reinterpret_cast<const uint2*>(&Vc[rv * 64 + ((cg1 ^ (rv & 7)) * 8) + woff]);
          o[dd] = MFMA(av.v, bp.v, o[dd]);
        }
        __builtin_amdgcn_s_setprio(0);
      }
    }
    asm volatile("s_waitcnt lgkmcnt(0)" ::: "memory");   // LDS reads done before release
    __builtin_amdgcn_s_barrier();    // buf[cur] free for iter c+1's stage of chunk c+2
  }

  // ---- epilogue: each wave owns the full k-range of its 16 q-rows ----
  float l = lpart;
  l += __shfl_xor(l, 16);
  l += __shfl_xor(l, 32);
  float rinv = 1.0f / l;
  u16* Yp = Yb + ((size_t)b * S + qrow) * E + h * 64 + quad * 4;
#pragma unroll
  for (int dd = 0; dd < 4; dd++) {
    ushort4 y;
    y.x = f2b(o[dd][0] * rinv); y.y = f2b(o[dd][1] * rinv);
    y.z = f2b(o[dd][2] * rinv); y.w = f2b(o[dd][3] * rinv);
    *reinterpret_cast<ushort4*>(Yp + dd * 16) = y;
  }
}

// ---------------- GEMM2: out = Yb @ wpbT^T, 128x64 tile (512 blocks = 2/CU), fp32 out ----
__global__ __launch_bounds__(256) void gemm_proj(const u16* __restrict__ A, const u16* __restrict__ BT,
                                                 float* __restrict__ out) {
  constexpr int K = 1024, BK = 64;
  __shared__ __align__(16) u16 As[128 * BK];   // 16 KB
  __shared__ __align__(16) u16 Bs[64 * BK];    // 8 KB
  int tid = threadIdx.x;
  int w = tid >> 6, lane = tid & 63, quad = lane >> 4, l15 = lane & 15;
  int m0 = blockIdx.x * 128, n0 = blockIdx.y * 64;
  int mw = (w >> 1) * 64, nw = (w & 1) * 32;
  const u16* Ab = A + (size_t)m0 * K;
  const u16* Bb = BT + (size_t)n0 * K;
  f32x4 acc[4][2] = {};
  for (int k0 = 0; k0 < K; k0 += BK) {
#pragma unroll
    for (int j = 0; j < 4; j++) {
      int L = j * 256 + tid;
      int row = L >> 3, cg = (L & 7) ^ (row & 7);
      G2L16(Ab + (size_t)row * K + k0 + cg * 8, (char*)As + L * 16);
    }
#pragma unroll
    for (int j = 0; j < 2; j++) {
      int L = j * 256 + tid;
      int row = L >> 3, cg = (L & 7) ^ (row & 7);
      G2L16(Bb + (size_t)row * K + k0 + cg * 8, (char*)Bs + L * 16);
    }
    __syncthreads();
#pragma unroll
    for (int kk = 0; kk < 2; kk++) {
      int sg = ((kk << 2) | quad) ^ (l15 & 7);
      bf16x8 a[4], b[2];
#pragma unroll
      for (int i = 0; i < 4; i++) a[i] = ld8(&As[(mw + i * 16 + l15) * BK + sg * 8]);
#pragma unroll
      for (int i = 0; i < 2; i++) b[i] = ld8(&Bs[(nw + i * 16 + l15) * BK + sg * 8]);
#pragma unroll
      for (int mb = 0; mb < 4; mb++)
#pragma unroll
        for (int nb = 0; nb < 2; nb++)
          acc[mb][nb] = MFMA(a[mb], b[nb], acc[mb][nb]);
    }
    __syncthreads();
  }
#pragma unroll
  for (int mb = 0; mb < 4; mb++) {
    int m = m0 + mw + mb * 16 + quad * 4;
#pragma unroll
    for (int nb = 0; nb < 2; nb++) {
      int n = n0 + nw + nb * 16 + l15;
#pragma unroll
      for (int r = 0; r < 4; r++)
        out[(size_t)(m + r) * E + n] = acc[mb][nb][r];
    }
  }
}

extern "C" void kernel_launch(void* const* d_in, const int* in_sizes, int n_in,
                              void* d_out, int out_size, void* d_ws, size_t ws_size,
                              hipStream_t stream) {
  const float* x = (const float*)d_in[0];
  const float* w_attn = (const float*)d_in[1];
  const float* w_proj = (const float*)d_in[2];
  float* out = (float*)d_out;
  char* ws = (char*)d_ws;

  // workspace layout (bytes)
  u16* xb   = (u16*)(ws);                      // 4096*1024*2 = 8 MB
  u16* wabT = (u16*)(ws + 8388608);            // 3072*1024*2 = 6 MB
  u16* wpbT = (u16*)(ws + 14680064);           // 1024*1024*2 = 2 MB
  u16* Qb   = (u16*)(ws + 16777216);           // 8 MB
  u16* Kb   = (u16*)(ws + 25165824);           // 8 MB
  u16* VbT  = (u16*)(ws + 33554432);           // 8 MB
  u16* Yb   = (u16*)(ws + 41943040);           // 8 MB   (total 48 MB)

  prep<<<8192, 256, 0, stream>>>(x, w_attn, w_proj, xb, wabT, wpbT);
  gemm_qkv<<<dim3(Mrows / 128, N_QKV / 64), 256, 0, stream>>>(xb, wabT, Qb, Kb, VbT);
  attn<<<Bn * H * (S / 64), 256, 0, stream>>>(Qb, Kb, VbT, Yb);
  gemm_proj<<<dim3(Mrows / 128, E / 64), 256, 0, stream>>>(Yb, wpbT, out);
}

// Round 6
// 167.969 us; speedup vs baseline: 1.0563x; 1.0563x over previous
//
#include <hip/hip_runtime.h>

#define DEVI __device__ __forceinline__

typedef short bf16x8 __attribute__((ext_vector_type(8)));
typedef float f32x4 __attribute__((ext_vector_type(4)));
typedef unsigned short u16;
typedef unsigned int u32;

// Problem constants
static constexpr int Bn = 2, S = 2048, E = 1024, H = 16, D = 64;
static constexpr int Mrows = Bn * S;          // 4096
static constexpr int N_QKV = 3 * E;           // 3072

DEVI u16 f2b(float f) {
  union { float f; u32 u; } c; c.f = f;
  return (u16)((c.u + 0x7FFFu + ((c.u >> 16) & 1u)) >> 16);
}

DEVI bf16x8 ld8(const u16* p) {
  union { uint4 u; bf16x8 v; } c;
  c.u = *reinterpret_cast<const uint4*>(p);
  return c.v;
}

#define MFMA(a, b, c) __builtin_amdgcn_mfma_f32_16x16x32_bf16(a, b, c, 0, 0, 0)

// global -> LDS async copy, 16B per lane. LDS dest must be wave-uniform-base + lane*16.
#define G2L16(gptr, lptr) \
  __builtin_amdgcn_global_load_lds((const __attribute__((address_space(1))) void*)(gptr), \
                                   (__attribute__((address_space(3))) void*)(lptr), 16, 0, 0)

// ---------------- Fused prep: transposes FIRST, conv LAST (r14 order) ----------------
__global__ __launch_bounds__(256) void prep(const float* __restrict__ x,
                                            const float* __restrict__ w_attn,
                                            const float* __restrict__ w_proj,
                                            u16* __restrict__ xb, u16* __restrict__ wabT,
                                            u16* __restrict__ wpbT) {
  __shared__ float t[32][33];
  int blk = blockIdx.x, tid = threadIdx.x;
  if (blk >= 4096) {
    int i = (blk - 4096) * 256 + tid;          // n4 = 4096*1024/4 = 1048576
    float4 f = reinterpret_cast<const float4*>(x)[i];
    ushort4 u;
    u.x = f2b(f.x); u.y = f2b(f.y); u.z = f2b(f.z); u.w = f2b(f.w);
    reinterpret_cast<ushort4*>(xb)[i] = u;
    return;
  }
  const float* in; u16* out; int R, C, bx, by;
  if (blk < 3072) {
    in = w_attn; out = wabT; R = E; C = N_QKV;  // 96 x 32 tiles
    bx = (blk % 96) * 32; by = (blk / 96) * 32;
  } else {
    int q = blk - 3072;                         // 32 x 32 tiles
    in = w_proj; out = wpbT; R = E; C = E;
    bx = (q % 32) * 32; by = (q / 32) * 32;
  }
  int tx = tid & 31, ty = tid >> 5;             // 32 x 8
#pragma unroll
  for (int k = 0; k < 32; k += 8)
    t[ty + k][tx] = in[(size_t)(by + ty + k) * C + bx + tx];
  __syncthreads();
#pragma unroll
  for (int k = 0; k < 32; k += 8)
    out[(size_t)(bx + ty + k) * R + by + tx] = f2b(t[tx][ty + k]);
}

// ---------------- GEMM1: qkv = xb @ wabT^T, 128x64 tile, BK=64, XOR swizzle (r14) ---------
// r19: 128x128 tile REVERTED (r18: 510 TF, 50.6us, Occ 14%). Short K (16 steps) +
// scatter epilogue + halved grid lose more to occupancy/tails than doubled B-reuse gains.
// Q pre-scaled by log2e/8 so attn scores arrive in log2 domain (exp2 = bare v_exp_f32).
__global__ __launch_bounds__(256) void gemm_qkv(const u16* __restrict__ A, const u16* __restrict__ BT,
                                                u16* __restrict__ Qb, u16* __restrict__ Kb,
                                                u16* __restrict__ VbT) {
  constexpr int K = 1024, BK = 64;
  __shared__ __align__(16) u16 As[128 * BK];   // 16 KB, swizzled rows of 8 16B-groups
  __shared__ __align__(16) u16 Bs[64 * BK];    // 8 KB
  int tid = threadIdx.x;
  int w = tid >> 6, lane = tid & 63, quad = lane >> 4, l15 = lane & 15;
  int m0 = blockIdx.x * 128, n0 = blockIdx.y * 64;
  int mw = (w >> 1) * 64, nw = (w & 1) * 32;   // wave-tile 64x32
  const u16* Ab = A + (size_t)m0 * K;
  const u16* Bb = BT + (size_t)n0 * K;
  f32x4 acc[4][2] = {};
  for (int k0 = 0; k0 < K; k0 += BK) {
#pragma unroll
    for (int j = 0; j < 4; j++) {
      int L = j * 256 + tid;
      int row = L >> 3, cg = (L & 7) ^ (row & 7);
      G2L16(Ab + (size_t)row * K + k0 + cg * 8, (char*)As + L * 16);
    }
#pragma unroll
    for (int j = 0; j < 2; j++) {
      int L = j * 256 + tid;
      int row = L >> 3, cg = (L & 7) ^ (row & 7);
      G2L16(Bb + (size_t)row * K + k0 + cg * 8, (char*)Bs + L * 16);
    }
    __syncthreads();
#pragma unroll
    for (int kk = 0; kk < 2; kk++) {
      int sg = ((kk << 2) | quad) ^ (l15 & 7);   // swizzled 16B-group for this lane
      bf16x8 a[4], b[2];
#pragma unroll
      for (int i = 0; i < 4; i++) a[i] = ld8(&As[(mw + i * 16 + l15) * BK + sg * 8]);
#pragma unroll
      for (int i = 0; i < 2; i++) b[i] = ld8(&Bs[(nw + i * 16 + l15) * BK + sg * 8]);
#pragma unroll
      for (int mb = 0; mb < 4; mb++)
#pragma unroll
        for (int nb = 0; nb < 2; nb++)
          acc[mb][nb] = MFMA(a[mb], b[nb], acc[mb][nb]);
    }
    __syncthreads();
  }
#pragma unroll
  for (int mb = 0; mb < 4; mb++) {
    int m = m0 + mw + mb * 16 + quad * 4;      // rows m..m+3 (tiles never straddle batch)
    int b = m >> 11, s = m & 2047;
#pragma unroll
    for (int nb = 0; nb < 2; nb++) {
      int n = n0 + nw + nb * 16 + l15;
      int sec = n >> 10, e = n & 1023, h = e >> 6, d = e & 63;
      int bh = b * H + h;
      if (sec == 0) {
#pragma unroll
        for (int r = 0; r < 4; r++)
          Qb[((size_t)bh * S + s + r) * D + d] = f2b(acc[mb][nb][r] * 0.1803368801111244f);
      } else if (sec == 1) {
#pragma unroll
        for (int r = 0; r < 4; r++)
          Kb[((size_t)bh * S + s + r) * D + d] = f2b(acc[mb][nb][r]);
      } else {
        ushort4 v;
        v.x = f2b(acc[mb][nb][0]); v.y = f2b(acc[mb][nb][1]);
        v.z = f2b(acc[mb][nb][2]); v.w = f2b(acc[mb][nb][3]);
        *reinterpret_cast<ushort4*>(VbT + ((size_t)bh * D + d) * S + s) = v;
      }
    }
  }
}

// ---------------- Flash attention: r0 skeleton + register-P (r22) ----------------
// Cross-round ledger: r0 (128-key chunk, single-buf, LDS-P, 3/CU) = 43.6us BEST;
// r19 (P-slice interleave) 50.4; r20 (64-key dbuf, counted vmcnt) 49.6;
// r21 (64-key + register-P) 51.9. Diagnosis: 64-key chunks double per-chunk fixed
// costs (2 barriers + guards); r21's 4.26M bank conflicts came from the 64-wide Vs
// swizzle (XOR over rv&7=l15&7 -> lanes l15,l15+8 share bank-pair -> 4-way), NOT from
// register-P itself. r22 = r0's proven 128-key single-buffer __syncthreads skeleton +
// r21's HW-verified register-P: QK^T C-layout leaves lane (quad,l15) holding keys
// {s*16+quad*4+r}; under kappa=quad*8+j -> (j<4 ? quad*4+j : 16+quad*4+j-4) the lane's
// own packed u32s ARE the PV B-operand; V read with the SAME key order = two b64s at
// groups cg0=ch*4+(quad>>1), cg1=cg0+2, offset (quad&1)*4. With the 128-wide Vs tile
// the XOR spans rv&15=l15 (full 4 bits) -> each bank-pair gets exactly 2 lanes = FREE.
// P LDS + its ds_write->lgkmcnt->ds_read serial chain deleted; LDS 49.8K -> 32K ->
// 4 blocks/CU = 16 waves. 1024 blocks now exactly co-resident (no backfill) ->
// heavy-first replaced by balanced qt permutation (quadruples {a,15-a,16+a,31-a}).
// Fixed-max log2-domain softmax; exp2+perm pack; T5 setprio on MFMA clusters.
__global__ __launch_bounds__(256, 4) void attn(const u16* __restrict__ Qb, const u16* __restrict__ Kb,
                                               const u16* __restrict__ VbT, u16* __restrict__ Yb) {
  __shared__ __align__(16) u16 Ks[128 * 64];    // swizzled: (row, cg) at row*64 + (cg^(row&7))*8
  __shared__ __align__(16) u16 Vs[64 * 128];    // swizzled: (d, cg) at d*128 + (cg^(d&15))*8
  int w = threadIdx.x >> 6, lane = threadIdx.x & 63, quad = lane >> 4, l15 = lane & 15;
  int bh = blockIdx.x & 31;          // same-bh -> same-XCD (blk%8 == bh%8)
  int g = blockIdx.x >> 5;           // 0..31
  int ga = g & 7, gb = g >> 3;
  int qt = ((gb & 2) << 3) + ((gb & 1) ? (15 - ga) : ga);   // balanced work permutation
  int b = bh >> 4, h = bh & 15;
  int nc = (qt + 2) >> 1;            // staged 128-key chunks

  const u16* Kbh = Kb + (size_t)bh * S * D;
  const u16* Vbh = VbT + (size_t)bh * D * S;

  int q_base = qt * 64 + w * 16;
  int qrow = q_base + l15;
  int kmax = q_base + 16;            // causal: this wave needs keys [0, kmax)

  const u16* Qp = Qb + ((size_t)bh * S + qrow) * D + quad * 8;
  bf16x8 bq0 = ld8(Qp), bq1 = ld8(Qp + 32);

  float lpart = 0.f;
  f32x4 o[4] = {};

  for (int c = 0; c < nc; c++) {
    int kbase = c * 128;
    __syncthreads();                 // previous chunk's readers done
    // ---- cooperative staging: K tile (16KB) ----
    const u16* Kg = Kbh + (size_t)kbase * D;
#pragma unroll
    for (int j = 0; j < 4; j++) {
      int L = (w * 4 + j) * 64 + lane;
      int row = L >> 3, cg = (L & 7) ^ (row & 7);
      G2L16(Kg + (size_t)row * 64 + cg * 8, (char*)Ks + L * 16);
    }
    // ---- cooperative staging: V^T tile (16KB) ----
    const u16* Vg = Vbh + kbase;
#pragma unroll
    for (int j = 0; j < 4; j++) {
      int L = (w * 4 + j) * 64 + lane;
      int row = L >> 4, cg = (L & 15) ^ (row & 15);
      G2L16(Vg + (size_t)row * S + cg * 8, (char*)Vs + L * 16);
    }
    __syncthreads();                 // staging visible (barrier drains vmcnt)

    // ---- per 32-key chunk: QK^T pair -> packed P in registers -> PV ----
#pragma unroll
    for (int ch = 0; ch < 4; ch++) {
      int kc = kbase + ch * 32;
      if (kc < kmax) {               // wave-uniform
        u32 pw0 = 0, pw1 = 0, pw2 = 0, pw3 = 0;   // pa_s0, pb_s0, pa_s1, pb_s1
#pragma unroll
        for (int s = 0; s < 2; s++) {
          int kb = kc + s * 16;
          if (kb < kmax) {           // wave-uniform
            int row = (ch * 2 + s) * 16 + l15;
            bf16x8 ak0 = ld8(&Ks[row * 64 + ((quad ^ (row & 7)) * 8)]);
            bf16x8 ak1 = ld8(&Ks[row * 64 + (((quad + 4) ^ (row & 7)) * 8)]);
            f32x4 z = {};
            __builtin_amdgcn_s_setprio(1);
            z = MFMA(ak0, bq0, z);
            z = MFMA(ak1, bq1, z);
            __builtin_amdgcn_s_setprio(0);
            if (kb == q_base) {      // diagonal subtile: mask k > q
#pragma unroll
              for (int r = 0; r < 4; r++)
                if (quad * 4 + r > l15) z[r] = -1e30f;
            }
            float p0 = __builtin_amdgcn_exp2f(z[0]);
            float p1 = __builtin_amdgcn_exp2f(z[1]);
            float p2 = __builtin_amdgcn_exp2f(z[2]);
            float p3 = __builtin_amdgcn_exp2f(z[3]);
            lpart += (p0 + p1) + (p2 + p3);
            union { float f; u32 u; } c0, c1, c2, c3;
            c0.f = p0; c1.f = p1; c2.f = p2; c3.f = p3;
            u32 pa = __builtin_amdgcn_perm(c1.u + 0x8000u, c0.u + 0x8000u, 0x07060302u);
            u32 pb = __builtin_amdgcn_perm(c3.u + 0x8000u, c2.u + 0x8000u, 0x07060302u);
            if (s == 0) { pw0 = pa; pw1 = pb; } else { pw2 = pa; pw3 = pb; }
          }
        }
        // B operand = own registers under key perm: kappa=quad*8+j -> keys
        // {kc+quad*4+0..3, kc+16+quad*4+0..3}. V read with the SAME key order.
        union { u32 u[4]; bf16x8 v; } bp;
        bp.u[0] = pw0; bp.u[1] = pw1; bp.u[2] = pw2; bp.u[3] = pw3;
        int cg0 = ch * 4 + (quad >> 1), cg1 = cg0 + 2;   // 16B-groups within 128-wide row
        int woff = (quad & 1) * 4;                       // u16 offset within group
        __builtin_amdgcn_s_setprio(1);
#pragma unroll
        for (int dd = 0; dd < 4; dd++) {
          int rv = dd * 16 + l15;
          union { uint2 d[2]; bf16x8 v; } av;
          av.d[0] = *reinterpret_cast<const uint2*>(&Vs[rv * 128 + ((cg0 ^ (rv & 15)) * 8) + woff]);
          av.d[1] = *reinterpret_cast<const uint2*>(&Vs[rv * 128 + ((cg1 ^ (rv & 15)) * 8) + woff]);
          o[dd] = MFMA(av.v, bp.v, o[dd]);
        }
        __builtin_amdgcn_s_setprio(0);
      }
    }
  }

  // ---- epilogue: each wave owns the full k-range of its 16 q-rows ----
  float l = lpart;
  l += __shfl_xor(l, 16);
  l += __shfl_xor(l, 32);
  float rinv = 1.0f / l;
  u16* Yp = Yb + ((size_t)b * S + qrow) * E + h * 64 + quad * 4;
#pragma unroll
  for (int dd = 0; dd < 4; dd++) {
    ushort4 y;
    y.x = f2b(o[dd][0] * rinv); y.y = f2b(o[dd][1] * rinv);
    y.z = f2b(o[dd][2] * rinv); y.w = f2b(o[dd][3] * rinv);
    *reinterpret_cast<ushort4*>(Yp + dd * 16) = y;
  }
}

// ---------------- GEMM2: out = Yb @ wpbT^T, 128x64 tile (512 blocks = 2/CU), fp32 out ----
__global__ __launch_bounds__(256) void gemm_proj(const u16* __restrict__ A, const u16* __restrict__ BT,
                                                 float* __restrict__ out) {
  constexpr int K = 1024, BK = 64;
  __shared__ __align__(16) u16 As[128 * BK];   // 16 KB
  __shared__ __align__(16) u16 Bs[64 * BK];    // 8 KB
  int tid = threadIdx.x;
  int w = tid >> 6, lane = tid & 63, quad = lane >> 4, l15 = lane & 15;
  int m0 = blockIdx.x * 128, n0 = blockIdx.y * 64;
  int mw = (w >> 1) * 64, nw = (w & 1) * 32;
  const u16* Ab = A + (size_t)m0 * K;
  const u16* Bb = BT + (size_t)n0 * K;
  f32x4 acc[4][2] = {};
  for (int k0 = 0; k0 < K; k0 += BK) {
#pragma unroll
    for (int j = 0; j < 4; j++) {
      int L = j * 256 + tid;
      int row = L >> 3, cg = (L & 7) ^ (row & 7);
      G2L16(Ab + (size_t)row * K + k0 + cg * 8, (char*)As + L * 16);
    }
#pragma unroll
    for (int j = 0; j < 2; j++) {
      int L = j * 256 + tid;
      int row = L >> 3, cg = (L & 7) ^ (row & 7);
      G2L16(Bb + (size_t)row * K + k0 + cg * 8, (char*)Bs + L * 16);
    }
    __syncthreads();
#pragma unroll
    for (int kk = 0; kk < 2; kk++) {
      int sg = ((kk << 2) | quad) ^ (l15 & 7);
      bf16x8 a[4], b[2];
#pragma unroll
      for (int i = 0; i < 4; i++) a[i] = ld8(&As[(mw + i * 16 + l15) * BK + sg * 8]);
#pragma unroll
      for (int i = 0; i < 2; i++) b[i] = ld8(&Bs[(nw + i * 16 + l15) * BK + sg * 8]);
#pragma unroll
      for (int mb = 0; mb < 4; mb++)
#pragma unroll
        for (int nb = 0; nb < 2; nb++)
          acc[mb][nb] = MFMA(a[mb], b[nb], acc[mb][nb]);
    }
    __syncthreads();
  }
#pragma unroll
  for (int mb = 0; mb < 4; mb++) {
    int m = m0 + mw + mb * 16 + quad * 4;
#pragma unroll
    for (int nb = 0; nb < 2; nb++) {
      int n = n0 + nw + nb * 16 + l15;
#pragma unroll
      for (int r = 0; r < 4; r++)
        out[(size_t)(m + r) * E + n] = acc[mb][nb][r];
    }
  }
}

extern "C" void kernel_launch(void* const* d_in, const int* in_sizes, int n_in,
                              void* d_out, int out_size, void* d_ws, size_t ws_size,
                              hipStream_t stream) {
  const float* x = (const float*)d_in[0];
  const float* w_attn = (const float*)d_in[1];
  const float* w_proj = (const float*)d_in[2];
  float* out = (float*)d_out;
  char* ws = (char*)d_ws;

  // workspace layout (bytes)
  u16* xb   = (u16*)(ws);                      // 4096*1024*2 = 8 MB
  u16* wabT = (u16*)(ws + 8388608);            // 3072*1024*2 = 6 MB
  u16* wpbT = (u16*)(ws + 14680064);           // 1024*1024*2 = 2 MB
  u16* Qb   = (u16*)(ws + 16777216);           // 8 MB
  u16* Kb   = (u16*)(ws + 25165824);           // 8 MB
  u16* VbT  = (u16*)(ws + 33554432);           // 8 MB
  u16* Yb   = (u16*)(ws + 41943040);           // 8 MB   (total 48 MB)

  prep<<<8192, 256, 0, stream>>>(x, w_attn, w_proj, xb, wabT, wpbT);
  gemm_qkv<<<dim3(Mrows / 128, N_QKV / 64), 256, 0, stream>>>(xb, wabT, Qb, Kb, VbT);
  attn<<<Bn * H * (S / 64), 256, 0, stream>>>(Qb, Kb, VbT, Yb);
  gemm_proj<<<dim3(Mrows / 128, E / 64), 256, 0, stream>>>(Yb, wpbT, out);
}